// Round 6
// baseline (484.476 us; speedup 1.0000x reference)
//
#include <hip/hip_runtime.h>
#include <hip/hip_bf16.h>
#include <stdint.h>

// MoE: E=8 experts, M=4096 tokens, K=2048 hidden, I=1408 intermediate, TOPK=2
#define EXPERTS 8
#define MTOK 4096
#define KDIM 2048
#define IDIM 1408
#define NDIM 2816   // 2*I
#define CAP  8192   // per-expert bucket capacity (worst case)

typedef __attribute__((ext_vector_type(8))) short bf16x8;
typedef __attribute__((ext_vector_type(4))) float f32x4;

__device__ __forceinline__ unsigned short f2bf(float x) {
    unsigned u = __float_as_uint(x);
    u = u + 0x7fffu + ((u >> 16) & 1u);   // RNE
    return (unsigned short)(u >> 16);
}

__device__ __forceinline__ void gload16(const void* g, void* l) {
    __builtin_amdgcn_global_load_lds(
        (const __attribute__((address_space(1))) void*)g,
        (__attribute__((address_space(3))) void*)l, 16, 0, 0);
}

// ---------------- fp32 -> bf16 conversion (vectorized) ----------------
__global__ void __launch_bounds__(256) conv_bf16(const float* __restrict__ src,
                                                 unsigned short* __restrict__ dst, int n4) {
    int i = blockIdx.x * 256 + threadIdx.x;
    int st = gridDim.x * 256;
    for (; i < n4; i += st) {
        float4 v = reinterpret_cast<const float4*>(src)[i];
        ushort4 r;
        r.x = f2bf(v.x); r.y = f2bf(v.y); r.z = f2bf(v.z); r.w = f2bf(v.w);
        reinterpret_cast<ushort4*>(dst)[i] = r;
    }
}

// ---------------- router ----------------
__global__ void __launch_bounds__(256) router(const float* __restrict__ tw,
                                              const int* __restrict__ ids,
                                              int* __restrict__ tok, float* __restrict__ wgt,
                                              int* __restrict__ cnt) {
    int m = blockIdx.x * 256 + threadIdx.x;
    if (m >= MTOK) return;
#pragma unroll
    for (int t = 0; t < 2; t++) {
        int e = ids[m * 2 + t];
        int slot = atomicAdd(&cnt[e], 1);
        tok[e * CAP + slot] = m;
        wgt[e * CAP + slot] = tw[m * 2 + t];
    }
}

__global__ void scan_off(const int* __restrict__ cnt, int* __restrict__ off) {
    if (threadIdx.x == 0) {
        int s = 0;
        for (int e = 0; e < EXPERTS; e++) { off[e] = s; s += cnt[e]; }
    }
}

// ====================================================================
// Ring GEMMs: 128x256 tile, BK=64, 8 waves (2Mx4N), 3-slot LDS ring,
// 2-tiles-ahead prefetch, counted vmcnt(6), 4 phases/K-tile, setprio.
// Expert->XCD pinning: linear grid, bid = j*8 + e  =>  XCD(bid%8)==e.
// LDS slot (48KB): A[128 rows][128B] at +0, B[256 rows][128B] at +16384.
// Swizzle: 16B slot g_phys = g_log ^ (row&7); inverse-permuted source.
// ====================================================================

// ---------------- GEMM1 + SiLU*up -> act (bf16) ----------------
__global__ void __launch_bounds__(512, 2) gemm1_silu(
    const unsigned short* __restrict__ hsb,
    const unsigned short* __restrict__ w1b,
    const int* __restrict__ tok,
    const int* __restrict__ cnt,
    const int* __restrict__ off,
    unsigned short* __restrict__ act) {
    const int bid = blockIdx.x;
    const int e = bid & 7;       // XCD pin
    const int j = bid >> 3;
    const int rb = j / 11;       // rb-major: co-resident blocks share A rows
    const int cb = j - rb * 11;  // 0..10 (11 * 128 = 1408 I-cols)
    const int cnt_e = cnt[e];
    if (rb * 128 >= cnt_e) return;
    const int off_e = off[e];
    const int NT = KDIM / 64;    // 32

    __shared__ __align__(16) char smem[147456];   // 3 x 48KB ring
    __shared__ int toks[128];

    const int tid = threadIdx.x;
    const int lane = tid & 63;
    const int w = tid >> 6;
    if (tid < 128) {
        int slot = rb * 128 + tid;
        toks[tid] = (slot < cnt_e) ? tok[e * CAP + slot] : 0;
    }
    __syncthreads();

    // ---- staging sources: 6 x 16B chunks per thread (A:2, B:4), linear LDS dest
    size_t sA[2]; int dA[2];
#pragma unroll
    for (int c = 0; c < 2; c++) {
        int i = c * 512 + tid;
        int row = i >> 3, gp = i & 7, gl = gp ^ (row & 7);
        sA[c] = (size_t)toks[row] * KDIM + gl * 8;
        dA[c] = i * 16;
    }
    size_t sB[4]; int dB[4];
    const size_t w1base = (size_t)e * (size_t)NDIM * KDIM;
#pragma unroll
    for (int c = 0; c < 4; c++) {
        int jj = c * 512 + tid;
        int row = jj >> 3, gp = jj & 7, gl = gp ^ (row & 7);
        int G = row >> 4;   // even = gate row, odd = up row (same 16-col slice)
        int w1row = ((G & 1) ? IDIM : 0) + cb * 128 + (G >> 1) * 16 + (row & 15);
        sB[c] = w1base + (size_t)w1row * KDIM + gl * 8;
        dB[c] = 16384 + jj * 16;
    }

    // ---- reader fragment offsets
    const int wr = w >> 2, wc = w & 3;   // 2M x 4N wave grid, wave tile 64x64
    const int l16 = lane & 15, lg = lane >> 4;
    int aoff[4][2], boff[4][2];
#pragma unroll
    for (int m = 0; m < 4; m++) {
        int row = wr * 64 + m * 16 + l16;
#pragma unroll
        for (int h = 0; h < 2; h++)
            aoff[m][h] = row * 128 + (((h * 4 + lg) ^ (row & 7)) * 16);
    }
#pragma unroll
    for (int n = 0; n < 4; n++) {
        int row = wc * 64 + n * 16 + l16;
#pragma unroll
        for (int h = 0; h < 2; h++)
            boff[n][h] = 16384 + row * 128 + (((h * 4 + lg) ^ (row & 7)) * 16);
    }

    f32x4 acc[4][4];
#pragma unroll
    for (int m = 0; m < 4; m++)
#pragma unroll
        for (int n = 0; n < 4; n++) acc[m][n] = {0.f, 0.f, 0.f, 0.f};

#define STG_A(t, base) { const int ko_ = (t) * 64; \
    gload16(hsb + sA[0] + ko_, (base) + dA[0]); \
    gload16(hsb + sA[1] + ko_, (base) + dA[1]); }
#define STG_B01(t, base) { const int ko_ = (t) * 64; \
    gload16(w1b + sB[0] + ko_, (base) + dB[0]); \
    gload16(w1b + sB[1] + ko_, (base) + dB[1]); }
#define STG_B23(t, base) { const int ko_ = (t) * 64; \
    gload16(w1b + sB[2] + ko_, (base) + dB[2]); \
    gload16(w1b + sB[3] + ko_, (base) + dB[3]); }

    // prologue: stage tiles 0 and 1; wait tile 0 (6 of 12 outstanding)
    STG_A(0, smem); STG_B01(0, smem); STG_B23(0, smem);
    { char* s1 = smem + 49152; STG_A(1, s1); STG_B01(1, s1); STG_B23(1, s1); }
    asm volatile("s_waitcnt vmcnt(6)" ::: "memory");
    __builtin_amdgcn_sched_barrier(0);
    __builtin_amdgcn_s_barrier();

    int cb_o = 0;        // ring byte offset of tile t
    int st_o = 98304;    // ring byte offset of tile t+2

#pragma unroll 1
    for (int t = 0; t < NT; ++t) {
        char* db = smem + cb_o;
        char* sb = smem + st_o;
        const bool stg = (t + 2 < NT);
        const int ko = (t + 2) * 64;

        // ---------- P0: read all B frags + A[0]; stage A
        bf16x8 bv0[4], bv1[4];
#pragma unroll
        for (int n = 0; n < 4; n++) {
            bv0[n] = *(const bf16x8*)(db + boff[n][0]);
            bv1[n] = *(const bf16x8*)(db + boff[n][1]);
        }
        bf16x8 a0 = *(const bf16x8*)(db + aoff[0][0]);
        bf16x8 a1 = *(const bf16x8*)(db + aoff[0][1]);
        if (stg) { gload16(hsb + sA[0] + ko, sb + dA[0]); gload16(hsb + sA[1] + ko, sb + dA[1]); }
        __builtin_amdgcn_sched_barrier(0);
        __builtin_amdgcn_s_barrier();
        asm volatile("s_waitcnt lgkmcnt(0)" ::: "memory");
        __builtin_amdgcn_sched_barrier(0);
        __builtin_amdgcn_s_setprio(1);
#pragma unroll
        for (int n = 0; n < 4; n++) acc[0][n] = __builtin_amdgcn_mfma_f32_16x16x32_bf16(a0, bv0[n], acc[0][n], 0, 0, 0);
#pragma unroll
        for (int n = 0; n < 4; n++) acc[0][n] = __builtin_amdgcn_mfma_f32_16x16x32_bf16(a1, bv1[n], acc[0][n], 0, 0, 0);
        __builtin_amdgcn_s_setprio(0);
        __builtin_amdgcn_sched_barrier(0);

        // ---------- P1: A[1]; stage B01
        a0 = *(const bf16x8*)(db + aoff[1][0]);
        a1 = *(const bf16x8*)(db + aoff[1][1]);
        if (stg) { gload16(w1b + sB[0] + ko, sb + dB[0]); gload16(w1b + sB[1] + ko, sb + dB[1]); }
        __builtin_amdgcn_sched_barrier(0);
        __builtin_amdgcn_s_barrier();
        asm volatile("s_waitcnt lgkmcnt(0)" ::: "memory");
        __builtin_amdgcn_sched_barrier(0);
        __builtin_amdgcn_s_setprio(1);
#pragma unroll
        for (int n = 0; n < 4; n++) acc[1][n] = __builtin_amdgcn_mfma_f32_16x16x32_bf16(a0, bv0[n], acc[1][n], 0, 0, 0);
#pragma unroll
        for (int n = 0; n < 4; n++) acc[1][n] = __builtin_amdgcn_mfma_f32_16x16x32_bf16(a1, bv1[n], acc[1][n], 0, 0, 0);
        __builtin_amdgcn_s_setprio(0);
        __builtin_amdgcn_sched_barrier(0);

        // ---------- P2: A[2]; stage B23
        a0 = *(const bf16x8*)(db + aoff[2][0]);
        a1 = *(const bf16x8*)(db + aoff[2][1]);
        if (stg) { gload16(w1b + sB[2] + ko, sb + dB[2]); gload16(w1b + sB[3] + ko, sb + dB[3]); }
        __builtin_amdgcn_sched_barrier(0);
        __builtin_amdgcn_s_barrier();
        asm volatile("s_waitcnt lgkmcnt(0)" ::: "memory");
        __builtin_amdgcn_sched_barrier(0);
        __builtin_amdgcn_s_setprio(1);
#pragma unroll
        for (int n = 0; n < 4; n++) acc[2][n] = __builtin_amdgcn_mfma_f32_16x16x32_bf16(a0, bv0[n], acc[2][n], 0, 0, 0);
#pragma unroll
        for (int n = 0; n < 4; n++) acc[2][n] = __builtin_amdgcn_mfma_f32_16x16x32_bf16(a1, bv1[n], acc[2][n], 0, 0, 0);
        __builtin_amdgcn_s_setprio(0);
        __builtin_amdgcn_sched_barrier(0);

        // ---------- P3: A[3]; no stage; counted vmcnt + ring barrier
        a0 = *(const bf16x8*)(db + aoff[3][0]);
        a1 = *(const bf16x8*)(db + aoff[3][1]);
        __builtin_amdgcn_sched_barrier(0);
        __builtin_amdgcn_s_barrier();
        asm volatile("s_waitcnt lgkmcnt(0)" ::: "memory");
        __builtin_amdgcn_sched_barrier(0);
        __builtin_amdgcn_s_setprio(1);
#pragma unroll
        for (int n = 0; n < 4; n++) acc[3][n] = __builtin_amdgcn_mfma_f32_16x16x32_bf16(a0, bv0[n], acc[3][n], 0, 0, 0);
#pragma unroll
        for (int n = 0; n < 4; n++) acc[3][n] = __builtin_amdgcn_mfma_f32_16x16x32_bf16(a1, bv1[n], acc[3][n], 0, 0, 0);
        __builtin_amdgcn_s_setprio(0);
        __builtin_amdgcn_sched_barrier(0);
        if (t + 2 < NT)      { asm volatile("s_waitcnt vmcnt(6)" ::: "memory"); }
        else if (t + 1 < NT) { asm volatile("s_waitcnt vmcnt(0)" ::: "memory"); }
        __builtin_amdgcn_sched_barrier(0);
        __builtin_amdgcn_s_barrier();

        cb_o += 49152; if (cb_o == 147456) cb_o = 0;
        st_o += 49152; if (st_o == 147456) st_o = 0;
    }
#undef STG_A
#undef STG_B01
#undef STG_B23

    // epilogue: within wave, n pairs (0,1),(2,3) are (gate,up) on same 16 cols
#pragma unroll
    for (int m = 0; m < 4; m++) {
#pragma unroll
        for (int p = 0; p < 2; p++) {
            f32x4 g4 = acc[m][p * 2];
            f32x4 u4 = acc[m][p * 2 + 1];
            int icol = cb * 128 + (wc * 2 + p) * 16 + l16;
#pragma unroll
            for (int j2 = 0; j2 < 4; j2++) {
                int grow = rb * 128 + wr * 64 + m * 16 + lg * 4 + j2;
                if (grow < cnt_e) {
                    float gt = g4[j2], up = u4[j2];
                    float s = gt / (1.f + __expf(-gt));
                    act[(size_t)(off_e + grow) * IDIM + icol] = f2bf(s * up);
                }
            }
        }
    }
}

// ---------------- GEMM2 + weighted scatter (ring structure) ----------------
__global__ void __launch_bounds__(512, 2) gemm2_scatter(
    const unsigned short* __restrict__ act,
    const unsigned short* __restrict__ w2b,
    const int* __restrict__ tok,
    const float* __restrict__ wgt,
    const int* __restrict__ cnt,
    const int* __restrict__ off,
    float* __restrict__ out) {
    const int bid = blockIdx.x;
    const int e = bid & 7;       // XCD pin
    const int j = bid >> 3;
    const int rb = j >> 3;       // rb-major
    const int cb = j & 7;        // 0..7 (8*256 = 2048 out cols)
    const int cnt_e = cnt[e];
    if (rb * 128 >= cnt_e) return;
    const int off_e = off[e];
    const int NT = IDIM / 64;    // 22

    __shared__ __align__(16) char smem[147456];
    __shared__ int toks[128];
    __shared__ float wgts[128];

    const int tid = threadIdx.x;
    const int lane = tid & 63;
    const int w = tid >> 6;
    if (tid < 128) {
        int slot = rb * 128 + tid;
        bool v = slot < cnt_e;
        toks[tid] = v ? tok[e * CAP + slot] : 0;
        wgts[tid] = v ? wgt[e * CAP + slot] : 0.f;
    }
    __syncthreads();

    size_t sA[2]; int dA[2];
#pragma unroll
    for (int c = 0; c < 2; c++) {
        int i = c * 512 + tid;
        int row = i >> 3, gp = i & 7, gl = gp ^ (row & 7);
        int s = rb * 128 + row;
        sA[c] = (size_t)(off_e + (s < cnt_e ? s : 0)) * IDIM + gl * 8;
        dA[c] = i * 16;
    }
    size_t sB[4]; int dB[4];
    const size_t w2base = (size_t)e * (size_t)KDIM * IDIM;
#pragma unroll
    for (int c = 0; c < 4; c++) {
        int jj = c * 512 + tid;
        int row = jj >> 3, gp = jj & 7, gl = gp ^ (row & 7);
        sB[c] = w2base + (size_t)(cb * 256 + row) * IDIM + gl * 8;
        dB[c] = 16384 + jj * 16;
    }

    const int wr = w >> 2, wc = w & 3;
    const int l16 = lane & 15, lg = lane >> 4;
    int aoff[4][2], boff[4][2];
#pragma unroll
    for (int m = 0; m < 4; m++) {
        int row = wr * 64 + m * 16 + l16;
#pragma unroll
        for (int h = 0; h < 2; h++)
            aoff[m][h] = row * 128 + (((h * 4 + lg) ^ (row & 7)) * 16);
    }
#pragma unroll
    for (int n = 0; n < 4; n++) {
        int row = wc * 64 + n * 16 + l16;
#pragma unroll
        for (int h = 0; h < 2; h++)
            boff[n][h] = 16384 + row * 128 + (((h * 4 + lg) ^ (row & 7)) * 16);
    }

    f32x4 acc[4][4];
#pragma unroll
    for (int m = 0; m < 4; m++)
#pragma unroll
        for (int n = 0; n < 4; n++) acc[m][n] = {0.f, 0.f, 0.f, 0.f};

#define STG2_A(t, base) { const int ko_ = (t) * 64; \
    gload16(act + sA[0] + ko_, (base) + dA[0]); \
    gload16(act + sA[1] + ko_, (base) + dA[1]); }
#define STG2_B01(t, base) { const int ko_ = (t) * 64; \
    gload16(w2b + sB[0] + ko_, (base) + dB[0]); \
    gload16(w2b + sB[1] + ko_, (base) + dB[1]); }
#define STG2_B23(t, base) { const int ko_ = (t) * 64; \
    gload16(w2b + sB[2] + ko_, (base) + dB[2]); \
    gload16(w2b + sB[3] + ko_, (base) + dB[3]); }

    STG2_A(0, smem); STG2_B01(0, smem); STG2_B23(0, smem);
    { char* s1 = smem + 49152; STG2_A(1, s1); STG2_B01(1, s1); STG2_B23(1, s1); }
    asm volatile("s_waitcnt vmcnt(6)" ::: "memory");
    __builtin_amdgcn_sched_barrier(0);
    __builtin_amdgcn_s_barrier();

    int cb_o = 0;
    int st_o = 98304;

#pragma unroll 1
    for (int t = 0; t < NT; ++t) {
        char* db = smem + cb_o;
        char* sb = smem + st_o;
        const bool stg = (t + 2 < NT);
        const int ko = (t + 2) * 64;

        bf16x8 bv0[4], bv1[4];
#pragma unroll
        for (int n = 0; n < 4; n++) {
            bv0[n] = *(const bf16x8*)(db + boff[n][0]);
            bv1[n] = *(const bf16x8*)(db + boff[n][1]);
        }
        bf16x8 a0 = *(const bf16x8*)(db + aoff[0][0]);
        bf16x8 a1 = *(const bf16x8*)(db + aoff[0][1]);
        if (stg) { gload16(act + sA[0] + ko, sb + dA[0]); gload16(act + sA[1] + ko, sb + dA[1]); }
        __builtin_amdgcn_sched_barrier(0);
        __builtin_amdgcn_s_barrier();
        asm volatile("s_waitcnt lgkmcnt(0)" ::: "memory");
        __builtin_amdgcn_sched_barrier(0);
        __builtin_amdgcn_s_setprio(1);
#pragma unroll
        for (int n = 0; n < 4; n++) acc[0][n] = __builtin_amdgcn_mfma_f32_16x16x32_bf16(a0, bv0[n], acc[0][n], 0, 0, 0);
#pragma unroll
        for (int n = 0; n < 4; n++) acc[0][n] = __builtin_amdgcn_mfma_f32_16x16x32_bf16(a1, bv1[n], acc[0][n], 0, 0, 0);
        __builtin_amdgcn_s_setprio(0);
        __builtin_amdgcn_sched_barrier(0);

        a0 = *(const bf16x8*)(db + aoff[1][0]);
        a1 = *(const bf16x8*)(db + aoff[1][1]);
        if (stg) { gload16(w2b + sB[0] + ko, sb + dB[0]); gload16(w2b + sB[1] + ko, sb + dB[1]); }
        __builtin_amdgcn_sched_barrier(0);
        __builtin_amdgcn_s_barrier();
        asm volatile("s_waitcnt lgkmcnt(0)" ::: "memory");
        __builtin_amdgcn_sched_barrier(0);
        __builtin_amdgcn_s_setprio(1);
#pragma unroll
        for (int n = 0; n < 4; n++) acc[1][n] = __builtin_amdgcn_mfma_f32_16x16x32_bf16(a0, bv0[n], acc[1][n], 0, 0, 0);
#pragma unroll
        for (int n = 0; n < 4; n++) acc[1][n] = __builtin_amdgcn_mfma_f32_16x16x32_bf16(a1, bv1[n], acc[1][n], 0, 0, 0);
        __builtin_amdgcn_s_setprio(0);
        __builtin_amdgcn_sched_barrier(0);

        a0 = *(const bf16x8*)(db + aoff[2][0]);
        a1 = *(const bf16x8*)(db + aoff[2][1]);
        if (stg) { gload16(w2b + sB[2] + ko, sb + dB[2]); gload16(w2b + sB[3] + ko, sb + dB[3]); }
        __builtin_amdgcn_sched_barrier(0);
        __builtin_amdgcn_s_barrier();
        asm volatile("s_waitcnt lgkmcnt(0)" ::: "memory");
        __builtin_amdgcn_sched_barrier(0);
        __builtin_amdgcn_s_setprio(1);
#pragma unroll
        for (int n = 0; n < 4; n++) acc[2][n] = __builtin_amdgcn_mfma_f32_16x16x32_bf16(a0, bv0[n], acc[2][n], 0, 0, 0);
#pragma unroll
        for (int n = 0; n < 4; n++) acc[2][n] = __builtin_amdgcn_mfma_f32_16x16x32_bf16(a1, bv1[n], acc[2][n], 0, 0, 0);
        __builtin_amdgcn_s_setprio(0);
        __builtin_amdgcn_sched_barrier(0);

        a0 = *(const bf16x8*)(db + aoff[3][0]);
        a1 = *(const bf16x8*)(db + aoff[3][1]);
        __builtin_amdgcn_sched_barrier(0);
        __builtin_amdgcn_s_barrier();
        asm volatile("s_waitcnt lgkmcnt(0)" ::: "memory");
        __builtin_amdgcn_sched_barrier(0);
        __builtin_amdgcn_s_setprio(1);
#pragma unroll
        for (int n = 0; n < 4; n++) acc[3][n] = __builtin_amdgcn_mfma_f32_16x16x32_bf16(a0, bv0[n], acc[3][n], 0, 0, 0);
#pragma unroll
        for (int n = 0; n < 4; n++) acc[3][n] = __builtin_amdgcn_mfma_f32_16x16x32_bf16(a1, bv1[n], acc[3][n], 0, 0, 0);
        __builtin_amdgcn_s_setprio(0);
        __builtin_amdgcn_sched_barrier(0);
        if (t + 2 < NT)      { asm volatile("s_waitcnt vmcnt(6)" ::: "memory"); }
        else if (t + 1 < NT) { asm volatile("s_waitcnt vmcnt(0)" ::: "memory"); }
        __builtin_amdgcn_sched_barrier(0);
        __builtin_amdgcn_s_barrier();

        cb_o += 49152; if (cb_o == 147456) cb_o = 0;
        st_o += 49152; if (st_o == 147456) st_o = 0;
    }
#undef STG2_A
#undef STG2_B01
#undef STG2_B23

    // scatter: out[token, k] += weight * y  (TOPK=2, fp32 atomic add, commutative)
#pragma unroll
    for (int m = 0; m < 4; m++) {
#pragma unroll
        for (int n = 0; n < 4; n++) {
            int kcol = cb * 256 + wc * 64 + n * 16 + l16;
#pragma unroll
            for (int j2 = 0; j2 < 4; j2++) {
                int lrow = wr * 64 + m * 16 + lg * 4 + j2;
                if (rb * 128 + lrow < cnt_e) {
                    atomicAdd(&out[(size_t)toks[lrow] * KDIM + kcol],
                              wgts[lrow] * acc[m][n][j2]);
                }
            }
        }
    }
}

extern "C" void kernel_launch(void* const* d_in, const int* in_sizes, int n_in,
                              void* d_out, int out_size, void* d_ws, size_t ws_size,
                              hipStream_t stream) {
    const float* hs  = (const float*)d_in[0];
    const float* w1  = (const float*)d_in[1];
    const float* w2  = (const float*)d_in[2];
    const float* tw  = (const float*)d_in[3];
    const int*   ids = (const int*)d_in[4];
    float* out = (float*)d_out;

    char* ws = (char*)d_ws;
    unsigned short* w1b  = (unsigned short*)(ws);                  //  92,274,688
    unsigned short* w2b  = (unsigned short*)(ws + 92274688ull);    //  46,137,344
    unsigned short* hsb  = (unsigned short*)(ws + 138412032ull);   //  16,777,216
    unsigned short* actb = (unsigned short*)(ws + 155189248ull);   //  23,068,672
    int*   tokb = (int*)  (ws + 178257920ull);
    float* wgtb = (float*)(ws + 178520064ull);
    int*   cntb = (int*)  (ws + 178782208ull);
    int*   offb = (int*)  (ws + 178782240ull);

    hipMemsetAsync(d_out, 0, (size_t)MTOK * KDIM * sizeof(float), stream);
    hipMemsetAsync(cntb, 0, 64, stream);

    conv_bf16<<<4096, 256, 0, stream>>>(w1, w1b, EXPERTS * NDIM * KDIM / 4);
    conv_bf16<<<2048, 256, 0, stream>>>(w2, w2b, EXPERTS * KDIM * IDIM / 4);
    conv_bf16<<<1024, 256, 0, stream>>>(hs, hsb, MTOK * KDIM / 4);

    router<<<MTOK / 256, 256, 0, stream>>>(tw, ids, tokb, wgtb, cntb);
    scan_off<<<1, 64, 0, stream>>>(cntb, offb);

    // linear grids with bid%8 == expert  (expert->XCD pinning)
    gemm1_silu<<<dim3(11 * 64 * 8, 1, 1), 512, 0, stream>>>(hsb, w1b, tokb, cntb, offb, actb);
    gemm2_scatter<<<dim3(8 * 64 * 8, 1, 1), 512, 0, stream>>>(actb, w2b, tokb, wgtb, cntb, offb, out);
}

// Round 7
// 472.011 us; speedup vs baseline: 1.0264x; 1.0264x over previous
//
#include <hip/hip_runtime.h>
#include <hip/hip_bf16.h>
#include <stdint.h>

// MoE: E=8 experts, M=4096 tokens, K=2048 hidden, I=1408 intermediate, TOPK=2
#define EXPERTS 8
#define MTOK 4096
#define KDIM 2048
#define IDIM 1408
#define NDIM 2816   // 2*I
#define CAP  8192   // per-expert bucket capacity (worst case)

typedef __attribute__((ext_vector_type(8))) short bf16x8;
typedef __attribute__((ext_vector_type(4))) float f32x4;

__device__ __forceinline__ unsigned short f2bf(float x) {
    unsigned u = __float_as_uint(x);
    u = u + 0x7fffu + ((u >> 16) & 1u);   // RNE
    return (unsigned short)(u >> 16);
}

__device__ __forceinline__ bf16x8 cvt8(float4 x, float4 y) {
    bf16x8 r;
    r[0] = (short)f2bf(x.x); r[1] = (short)f2bf(x.y);
    r[2] = (short)f2bf(x.z); r[3] = (short)f2bf(x.w);
    r[4] = (short)f2bf(y.x); r[5] = (short)f2bf(y.y);
    r[6] = (short)f2bf(y.z); r[7] = (short)f2bf(y.w);
    return r;
}

// ---------------- router ----------------
__global__ void __launch_bounds__(256) router(const float* __restrict__ tw,
                                              const int* __restrict__ ids,
                                              int* __restrict__ tok, float* __restrict__ wgt,
                                              int* __restrict__ cnt) {
    int m = blockIdx.x * 256 + threadIdx.x;
    if (m >= MTOK) return;
#pragma unroll
    for (int t = 0; t < 2; t++) {
        int e = ids[m * 2 + t];
        int slot = atomicAdd(&cnt[e], 1);
        tok[e * CAP + slot] = m;
        wgt[e * CAP + slot] = tw[m * 2 + t];
    }
}

__global__ void scan_off(const int* __restrict__ cnt, int* __restrict__ off) {
    if (threadIdx.x == 0) {
        int s = 0;
        for (int e = 0; e < EXPERTS; e++) { off[e] = s; s += cnt[e]; }
    }
}

// ====================================================================
// Direct-fp32 GEMMs, in-register fp32->bf16 during staging.
// 128x128 tile, BK=32, 256 thr (2x2 waves), expert->XCD pinning.
// Reg double-buffer (2-deep), counted vmcnt, ONE barrier per K-step:
//   [issue loads t+1] vmcnt(N) [cvt+ds_write buf(t&1)] lgkmcnt(0)
//   barrier [ds_read frags + 16 MFMA]
// LDS per buffer 16KB (A 8KB @ +0, B 8KB @ +8192), 2 buffers = 32KB.
// Rows 64B = 4 x 16B slots; swizzle phys = g ^ ((row>>1)&3) applied on
// BOTH ds_write and ds_read (reg-staged, so both sides controllable).
// ====================================================================

// ---------------- GEMM1 + SiLU*up -> act (bf16) ----------------
__global__ void __launch_bounds__(256, 2) gemm1_silu(
    const float* __restrict__ hs,
    const float* __restrict__ w1,
    const int* __restrict__ tok,
    const int* __restrict__ cnt,
    const int* __restrict__ off,
    unsigned short* __restrict__ act) {
    const int bid = blockIdx.x;
    const int e = bid & 7;       // XCD pin: bid%8 -> XCD
    const int j = bid >> 3;
    const int rb = j / 22;       // rb-major: co-resident blocks share A rows
    const int cb = j - rb * 22;  // 0..21 (22*64 = 1408 gate cols)
    const int cnt_e = cnt[e];
    if (rb * 128 >= cnt_e) return;
    const int off_e = off[e];
    const int NT = KDIM / 32;    // 64 (even)

    __shared__ __align__(16) char smem[32768];
    __shared__ int toks[128];

    const int tid = threadIdx.x;
    const int w = tid >> 6, lane = tid & 63;
    if (tid < 128) {
        int slot = rb * 128 + tid;
        toks[tid] = (slot < cnt_e) ? tok[e * CAP + slot] : 0;
    }
    __syncthreads();

    // ---- staging geometry: 2 A-slots + 2 B-slots (16B bf16 each) per thread
    // slot k: row = k>>2, g = k&3 (8 K-elems); phys = g ^ ((row>>1)&3)
    const int rA0 = tid >> 2, gA = tid & 3;
    const int rA1 = 64 + rA0;
    const size_t srcA0 = (size_t)toks[rA0] * KDIM + gA * 8;   // fp32 elems
    const size_t srcA1 = (size_t)toks[rA1] * KDIM + gA * 8;
    const int dA0 = rA0 * 64 + ((gA ^ ((rA0 >> 1) & 3)) * 16);
    const int dA1 = rA1 * 64 + ((gA ^ ((rA1 >> 1) & 3)) * 16);

    const size_t w1base = (size_t)e * (size_t)NDIM * KDIM;
    const int G0 = rA0 >> 4, G1 = rA1 >> 4;
    const int wrow0 = ((G0 & 1) ? IDIM : 0) + cb * 64 + (G0 >> 1) * 16 + (rA0 & 15);
    const int wrow1 = ((G1 & 1) ? IDIM : 0) + cb * 64 + (G1 >> 1) * 16 + (rA1 & 15);
    const size_t srcB0 = w1base + (size_t)wrow0 * KDIM + gA * 8;
    const size_t srcB1 = w1base + (size_t)wrow1 * KDIM + gA * 8;
    const int dB0 = 8192 + dA0;
    const int dB1 = 8192 + dA1;

    const int wr = w >> 1, wc = w & 1;
    const int l16 = lane & 15, lg = lane >> 4;
    int aoff[4], boff[4];
#pragma unroll
    for (int m = 0; m < 4; m++) {
        int r = wr * 64 + m * 16 + l16;
        aoff[m] = r * 64 + ((lg ^ ((r >> 1) & 3)) * 16);
    }
#pragma unroll
    for (int n = 0; n < 4; n++) {
        int r = wc * 64 + n * 16 + l16;
        boff[n] = 8192 + r * 64 + ((lg ^ ((r >> 1) & 3)) * 16);
    }

    f32x4 acc[4][4];
#pragma unroll
    for (int m = 0; m < 4; m++)
#pragma unroll
        for (int n = 0; n < 4; n++) acc[m][n] = {0.f, 0.f, 0.f, 0.f};

    struct RegT { float4 a00, a01, a10, a11, b00, b01, b10, b11; };
    RegT Ra, Rb;

#define LOADR1(R, t) { const int ko = (t) * 32; \
    R.a00 = *(const float4*)(hs + srcA0 + ko);     R.a01 = *(const float4*)(hs + srcA0 + ko + 4); \
    R.a10 = *(const float4*)(hs + srcA1 + ko);     R.a11 = *(const float4*)(hs + srcA1 + ko + 4); \
    R.b00 = *(const float4*)(w1 + srcB0 + ko);     R.b01 = *(const float4*)(w1 + srcB0 + ko + 4); \
    R.b10 = *(const float4*)(w1 + srcB1 + ko);     R.b11 = *(const float4*)(w1 + srcB1 + ko + 4); }
#define CVW1(R, base) { \
    *(bf16x8*)(smem + (base) + dA0) = cvt8(R.a00, R.a01); \
    *(bf16x8*)(smem + (base) + dA1) = cvt8(R.a10, R.a11); \
    *(bf16x8*)(smem + (base) + dB0) = cvt8(R.b00, R.b01); \
    *(bf16x8*)(smem + (base) + dB1) = cvt8(R.b10, R.b11); }
#define FRAG1(base) { bf16x8 af[4], bf[4]; \
    _Pragma("unroll") for (int m = 0; m < 4; m++) af[m] = *(const bf16x8*)(smem + (base) + aoff[m]); \
    _Pragma("unroll") for (int n = 0; n < 4; n++) bf[n] = *(const bf16x8*)(smem + (base) + boff[n]); \
    _Pragma("unroll") for (int m = 0; m < 4; m++) \
    _Pragma("unroll") for (int n = 0; n < 4; n++) \
        acc[m][n] = __builtin_amdgcn_mfma_f32_16x16x32_bf16(af[m], bf[n], acc[m][n], 0, 0, 0); }

    LOADR1(Ra, 0);
#pragma unroll 1
    for (int kt = 0; kt < NT; kt += 2) {
        // ---- even step: consume Ra -> buf0, prefetch Rb(kt+1)
        if (kt + 1 < NT) { LOADR1(Rb, kt + 1); asm volatile("s_waitcnt vmcnt(8)" ::: "memory"); }
        else             { asm volatile("s_waitcnt vmcnt(0)" ::: "memory"); }
        __builtin_amdgcn_sched_barrier(0);
        CVW1(Ra, 0);
        asm volatile("s_waitcnt lgkmcnt(0)" ::: "memory");
        __builtin_amdgcn_sched_barrier(0);
        __builtin_amdgcn_s_barrier();
        __builtin_amdgcn_sched_barrier(0);
        FRAG1(0);
        // ---- odd step: consume Rb -> buf1, prefetch Ra(kt+2)
        if (kt + 2 < NT) { LOADR1(Ra, kt + 2); asm volatile("s_waitcnt vmcnt(8)" ::: "memory"); }
        else             { asm volatile("s_waitcnt vmcnt(0)" ::: "memory"); }
        __builtin_amdgcn_sched_barrier(0);
        CVW1(Rb, 16384);
        asm volatile("s_waitcnt lgkmcnt(0)" ::: "memory");
        __builtin_amdgcn_sched_barrier(0);
        __builtin_amdgcn_s_barrier();
        __builtin_amdgcn_sched_barrier(0);
        FRAG1(16384);
    }
#undef LOADR1
#undef CVW1
#undef FRAG1

    // epilogue: n even = gate frag, n+1 = up frag (same 16 cols)
#pragma unroll
    for (int m = 0; m < 4; m++) {
#pragma unroll
        for (int np = 0; np < 2; np++) {
            f32x4 g4 = acc[m][np * 2];
            f32x4 u4 = acc[m][np * 2 + 1];
            int icol = cb * 64 + (wc * 2 + np) * 16 + l16;
#pragma unroll
            for (int j2 = 0; j2 < 4; j2++) {
                int grow = rb * 128 + wr * 64 + m * 16 + lg * 4 + j2;
                if (grow < cnt_e) {
                    float gt = g4[j2], up = u4[j2];
                    float s = gt / (1.f + __expf(-gt));
                    act[(size_t)(off_e + grow) * IDIM + icol] = f2bf(s * up);
                }
            }
        }
    }
}

// ---------------- GEMM2 + weighted scatter ----------------
__global__ void __launch_bounds__(256, 2) gemm2_scatter(
    const unsigned short* __restrict__ act,
    const float* __restrict__ w2,
    const int* __restrict__ tok,
    const float* __restrict__ wgt,
    const int* __restrict__ cnt,
    const int* __restrict__ off,
    float* __restrict__ out) {
    const int bid = blockIdx.x;
    const int e = bid & 7;       // XCD pin
    const int j = bid >> 3;
    const int rb = j >> 4;       // rb-major
    const int cb = j & 15;       // 0..15 (16*128 = 2048 out cols)
    const int cnt_e = cnt[e];
    if (rb * 128 >= cnt_e) return;
    const int off_e = off[e];
    const int NT = IDIM / 32;    // 44 (even)

    __shared__ __align__(16) char smem[32768];
    __shared__ int toks[128];
    __shared__ float wgts[128];

    const int tid = threadIdx.x;
    const int w = tid >> 6, lane = tid & 63;
    if (tid < 128) {
        int slot = rb * 128 + tid;
        bool v = slot < cnt_e;
        toks[tid] = v ? tok[e * CAP + slot] : 0;
        wgts[tid] = v ? wgt[e * CAP + slot] : 0.f;
    }
    __syncthreads();

    const int rA0 = tid >> 2, gA = tid & 3;
    const int rA1 = 64 + rA0;
    const int s0 = rb * 128 + rA0, s1 = rb * 128 + rA1;
    const size_t srcA0 = (size_t)(off_e + (s0 < cnt_e ? s0 : 0)) * IDIM + gA * 8;  // bf16 elems
    const size_t srcA1 = (size_t)(off_e + (s1 < cnt_e ? s1 : 0)) * IDIM + gA * 8;
    const int dA0 = rA0 * 64 + ((gA ^ ((rA0 >> 1) & 3)) * 16);
    const int dA1 = rA1 * 64 + ((gA ^ ((rA1 >> 1) & 3)) * 16);

    const size_t w2base = (size_t)e * (size_t)KDIM * IDIM;
    const size_t srcB0 = w2base + (size_t)(cb * 128 + rA0) * IDIM + gA * 8;   // fp32 elems
    const size_t srcB1 = w2base + (size_t)(cb * 128 + rA1) * IDIM + gA * 8;
    const int dB0 = 8192 + dA0;
    const int dB1 = 8192 + dA1;

    const int wr = w >> 1, wc = w & 1;
    const int l16 = lane & 15, lg = lane >> 4;
    int aoff[4], boff[4];
#pragma unroll
    for (int m = 0; m < 4; m++) {
        int r = wr * 64 + m * 16 + l16;
        aoff[m] = r * 64 + ((lg ^ ((r >> 1) & 3)) * 16);
    }
#pragma unroll
    for (int n = 0; n < 4; n++) {
        int r = wc * 64 + n * 16 + l16;
        boff[n] = 8192 + r * 64 + ((lg ^ ((r >> 1) & 3)) * 16);
    }

    f32x4 acc[4][4];
#pragma unroll
    for (int m = 0; m < 4; m++)
#pragma unroll
        for (int n = 0; n < 4; n++) acc[m][n] = {0.f, 0.f, 0.f, 0.f};

    struct RegT2 { uint4 aa0, aa1; float4 b00, b01, b10, b11; };
    RegT2 Ra, Rb;

#define LOADR2(R, t) { const int ko = (t) * 32; \
    R.aa0 = *(const uint4*)(act + srcA0 + ko); \
    R.aa1 = *(const uint4*)(act + srcA1 + ko); \
    R.b00 = *(const float4*)(w2 + srcB0 + ko); R.b01 = *(const float4*)(w2 + srcB0 + ko + 4); \
    R.b10 = *(const float4*)(w2 + srcB1 + ko); R.b11 = *(const float4*)(w2 + srcB1 + ko + 4); }
#define CVW2(R, base) { \
    *(uint4*)(smem + (base) + dA0) = R.aa0; \
    *(uint4*)(smem + (base) + dA1) = R.aa1; \
    *(bf16x8*)(smem + (base) + dB0) = cvt8(R.b00, R.b01); \
    *(bf16x8*)(smem + (base) + dB1) = cvt8(R.b10, R.b11); }
#define FRAG2(base) { bf16x8 af[4], bf[4]; \
    _Pragma("unroll") for (int m = 0; m < 4; m++) af[m] = *(const bf16x8*)(smem + (base) + aoff[m]); \
    _Pragma("unroll") for (int n = 0; n < 4; n++) bf[n] = *(const bf16x8*)(smem + (base) + boff[n]); \
    _Pragma("unroll") for (int m = 0; m < 4; m++) \
    _Pragma("unroll") for (int n = 0; n < 4; n++) \
        acc[m][n] = __builtin_amdgcn_mfma_f32_16x16x32_bf16(af[m], bf[n], acc[m][n], 0, 0, 0); }

    LOADR2(Ra, 0);
#pragma unroll 1
    for (int kt = 0; kt < NT; kt += 2) {
        if (kt + 1 < NT) { LOADR2(Rb, kt + 1); asm volatile("s_waitcnt vmcnt(6)" ::: "memory"); }
        else             { asm volatile("s_waitcnt vmcnt(0)" ::: "memory"); }
        __builtin_amdgcn_sched_barrier(0);
        CVW2(Ra, 0);
        asm volatile("s_waitcnt lgkmcnt(0)" ::: "memory");
        __builtin_amdgcn_sched_barrier(0);
        __builtin_amdgcn_s_barrier();
        __builtin_amdgcn_sched_barrier(0);
        FRAG2(0);
        if (kt + 2 < NT) { LOADR2(Ra, kt + 2); asm volatile("s_waitcnt vmcnt(6)" ::: "memory"); }
        else             { asm volatile("s_waitcnt vmcnt(0)" ::: "memory"); }
        __builtin_amdgcn_sched_barrier(0);
        CVW2(Rb, 16384);
        asm volatile("s_waitcnt lgkmcnt(0)" ::: "memory");
        __builtin_amdgcn_sched_barrier(0);
        __builtin_amdgcn_s_barrier();
        __builtin_amdgcn_sched_barrier(0);
        FRAG2(16384);
    }
#undef LOADR2
#undef CVW2
#undef FRAG2

    // scatter: out[token, k] += weight * y  (TOPK=2, fp32 atomic add, commutative)
#pragma unroll
    for (int m = 0; m < 4; m++) {
#pragma unroll
        for (int n = 0; n < 4; n++) {
            int kcol = cb * 128 + wc * 64 + n * 16 + l16;
#pragma unroll
            for (int j2 = 0; j2 < 4; j2++) {
                int lrow = wr * 64 + m * 16 + lg * 4 + j2;
                if (rb * 128 + lrow < cnt_e) {
                    atomicAdd(&out[(size_t)toks[lrow] * KDIM + kcol],
                              wgts[lrow] * acc[m][n][j2]);
                }
            }
        }
    }
}

extern "C" void kernel_launch(void* const* d_in, const int* in_sizes, int n_in,
                              void* d_out, int out_size, void* d_ws, size_t ws_size,
                              hipStream_t stream) {
    const float* hs  = (const float*)d_in[0];
    const float* w1  = (const float*)d_in[1];
    const float* w2  = (const float*)d_in[2];
    const float* tw  = (const float*)d_in[3];
    const int*   ids = (const int*)d_in[4];
    float* out = (float*)d_out;

    char* ws = (char*)d_ws;
    unsigned short* actb = (unsigned short*)(ws);            // 23,068,672 B
    int*   tokb = (int*)  (ws + 23068672ull);                //    262,144
    float* wgtb = (float*)(ws + 23330816ull);                //    262,144
    int*   cntb = (int*)  (ws + 23592960ull);                //         32
    int*   offb = (int*)  (ws + 23592992ull);                //         32

    hipMemsetAsync(d_out, 0, (size_t)MTOK * KDIM * sizeof(float), stream);
    hipMemsetAsync(cntb, 0, 64, stream);

    router<<<MTOK / 256, 256, 0, stream>>>(tw, ids, tokb, wgtb, cntb);
    scan_off<<<1, 64, 0, stream>>>(cntb, offb);

    // linear grids with bid%8 == expert  (expert->XCD pinning)
    gemm1_silu<<<dim3(22 * 64 * 8, 1, 1), 256, 0, stream>>>(hs, w1, tokb, cntb, offb, actb);
    gemm2_scatter<<<dim3(16 * 64 * 8, 1, 1), 256, 0, stream>>>(actb, w2, tokb, wgtb, cntb, offb, out);
}

// Round 8
// 393.684 us; speedup vs baseline: 1.2306x; 1.1990x over previous
//
#include <hip/hip_runtime.h>
#include <hip/hip_bf16.h>
#include <stdint.h>

// MoE: E=8 experts, M=4096 tokens, K=2048 hidden, I=1408 intermediate, TOPK=2
#define EXPERTS 8
#define MTOK 4096
#define KDIM 2048
#define IDIM 1408
#define NDIM 2816   // 2*I
#define CAP  8192   // per-expert bucket capacity (worst case)

typedef __attribute__((ext_vector_type(8))) short bf16x8;
typedef __attribute__((ext_vector_type(4))) float f32x4;

__device__ __forceinline__ unsigned short f2bf(float x) {
    unsigned u = __float_as_uint(x);
    u = u + 0x7fffu + ((u >> 16) & 1u);   // RNE
    return (unsigned short)(u >> 16);
}

__device__ __forceinline__ void gload16(const void* g, void* l) {
    __builtin_amdgcn_global_load_lds(
        (const __attribute__((address_space(1))) void*)g,
        (__attribute__((address_space(3))) void*)l, 16, 0, 0);
}

// ---------------- fp32 -> bf16 conversion (vectorized) ----------------
__global__ void __launch_bounds__(256) conv_bf16(const float* __restrict__ src,
                                                 unsigned short* __restrict__ dst, int n4) {
    int i = blockIdx.x * 256 + threadIdx.x;
    int st = gridDim.x * 256;
    for (; i < n4; i += st) {
        float4 v = reinterpret_cast<const float4*>(src)[i];
        ushort4 r;
        r.x = f2bf(v.x); r.y = f2bf(v.y); r.z = f2bf(v.z); r.w = f2bf(v.w);
        reinterpret_cast<ushort4*>(dst)[i] = r;
    }
}

// ---------------- router ----------------
__global__ void __launch_bounds__(256) router(const float* __restrict__ tw,
                                              const int* __restrict__ ids,
                                              int* __restrict__ tok, float* __restrict__ wgt,
                                              int* __restrict__ cnt) {
    int m = blockIdx.x * 256 + threadIdx.x;
    if (m >= MTOK) return;
#pragma unroll
    for (int t = 0; t < 2; t++) {
        int e = ids[m * 2 + t];
        int slot = atomicAdd(&cnt[e], 1);
        tok[e * CAP + slot] = m;
        wgt[e * CAP + slot] = tw[m * 2 + t];
    }
}

__global__ void scan_off(const int* __restrict__ cnt, int* __restrict__ off) {
    if (threadIdx.x == 0) {
        int s = 0;
        for (int e = 0; e < EXPERTS; e++) { off[e] = s; s += cnt[e]; }
    }
}

// ====================================================================
// Round-4 128x128/BK=32 GEMMs + 3-slot LDS ring (16KB/slot, 48KB total)
// with counted vmcnt(4): stage(t+2) issued at iter start, compute tile t,
// then vmcnt(4) (stage(t+1) done, stage(t+2) in flight) + raw s_barrier.
// Expert->XCD pinning: bid%8 == expert. Swizzle as round 4 (verified).
// ====================================================================

// ---------------- GEMM1 + SiLU*up -> act (bf16) ----------------
__global__ void __launch_bounds__(256, 3) gemm1_silu(
    const unsigned short* __restrict__ hsb,
    const unsigned short* __restrict__ w1b,
    const int* __restrict__ tok,
    const int* __restrict__ cnt,
    const int* __restrict__ off,
    unsigned short* __restrict__ act) {
    const int bid = blockIdx.x;
    const int e = bid & 7;       // XCD pin: bid%8 -> XCD
    const int j = bid >> 3;
    const int rb = j / 22;       // rb-major: co-resident blocks share A rows
    const int cb = j - rb * 22;  // 0..21 (22*64 = 1408 gate cols)
    const int cnt_e = cnt[e];
    if (rb * 128 >= cnt_e) return;
    const int off_e = off[e];
    const int NT = KDIM / 32;    // 64

    __shared__ __align__(16) char smem[49152];   // 3 x 16KB ring
    __shared__ int toks[128];

    const int tid = threadIdx.x;
    const int w = tid >> 6, lane = tid & 63;
    if (tid < 128) {
        int slot = rb * 128 + tid;
        toks[tid] = (slot < cnt_e) ? tok[e * CAP + slot] : 0;
    }
    __syncthreads();

    // staging geometry (round-4 verified): per-slot layout A@0(8KB), B@8192(8KB)
    // chunk dest o = region + w*1024 + lane*16; row = o>>6 (within region),
    // source k-group preswizzled: g = ((o>>4)&3) ^ ((row>>1)&3)
    const int o0 = w * 1024 + lane * 16;
    const int row0 = o0 >> 6, g0 = ((o0 >> 4) & 3) ^ ((row0 >> 1) & 3);
    const int o1 = 4096 + o0;
    const int row1 = o1 >> 6, g1 = ((o1 >> 4) & 3) ^ ((row1 >> 1) & 3);

    const int G0 = row0 >> 4, G1 = row1 >> 4;
    const size_t w1base = (size_t)e * NDIM * KDIM;
    const int wrow0 = ((G0 & 1) ? IDIM : 0) + cb * 64 + (G0 >> 1) * 16 + (row0 & 15);
    const int wrow1 = ((G1 & 1) ? IDIM : 0) + cb * 64 + (G1 >> 1) * 16 + (row1 & 15);

    const size_t srcA0 = (size_t)toks[row0] * KDIM + g0 * 8;
    const size_t srcA1 = (size_t)toks[row1] * KDIM + g1 * 8;
    const size_t srcB0 = w1base + (size_t)wrow0 * KDIM + g0 * 8;
    const size_t srcB1 = w1base + (size_t)wrow1 * KDIM + g1 * 8;

    const int wr = w >> 1, wc = w & 1;
    const int l16 = lane & 15, lg = lane >> 4;
    int aoff[4], boff[4];
#pragma unroll
    for (int m = 0; m < 4; m++) {
        int r = wr * 64 + m * 16 + l16;
        aoff[m] = r * 64 + ((lg ^ ((r >> 1) & 3)) * 16);
    }
#pragma unroll
    for (int n = 0; n < 4; n++) {
        int r = wc * 64 + n * 16 + l16;
        boff[n] = 8192 + r * 64 + ((lg ^ ((r >> 1) & 3)) * 16);
    }

    f32x4 acc[4][4];
#pragma unroll
    for (int m = 0; m < 4; m++)
#pragma unroll
        for (int n = 0; n < 4; n++) acc[m][n] = {0.f, 0.f, 0.f, 0.f};

#define STG1(t, base) { const int kof_ = (t) * 32; char* b_ = smem + (base); \
    gload16(hsb + srcA0 + kof_, b_ + w * 1024); \
    gload16(hsb + srcA1 + kof_, b_ + 4096 + w * 1024); \
    gload16(w1b + srcB0 + kof_, b_ + 8192 + w * 1024); \
    gload16(w1b + srcB1 + kof_, b_ + 12288 + w * 1024); }

    // prologue: stage tiles 0,1 into slots 0,1; wait tile 0 only
    STG1(0, 0); STG1(1, 16384);
    asm volatile("s_waitcnt vmcnt(4)" ::: "memory");
    __builtin_amdgcn_sched_barrier(0);
    __builtin_amdgcn_s_barrier();

    int sl_t = 0;        // slot byte base of tile t
    int sl_p = 32768;    // slot byte base of tile t+2

#pragma unroll 1
    for (int t = 0; t < NT; ++t) {
        if (t + 2 < NT) STG1(t + 2, sl_p);
        __builtin_amdgcn_sched_barrier(0);

        const char* db = smem + sl_t;
        bf16x8 af[4], bf[4];
#pragma unroll
        for (int m = 0; m < 4; m++) af[m] = *(const bf16x8*)(db + aoff[m]);
#pragma unroll
        for (int n = 0; n < 4; n++) bf[n] = *(const bf16x8*)(db + boff[n]);
        __builtin_amdgcn_s_setprio(1);
#pragma unroll
        for (int m = 0; m < 4; m++)
#pragma unroll
            for (int n = 0; n < 4; n++)
                acc[m][n] = __builtin_amdgcn_mfma_f32_16x16x32_bf16(af[m], bf[n], acc[m][n], 0, 0, 0);
        __builtin_amdgcn_s_setprio(0);
        __builtin_amdgcn_sched_barrier(0);
        if (t + 2 < NT)      { asm volatile("s_waitcnt vmcnt(4)" ::: "memory"); }
        else if (t + 1 < NT) { asm volatile("s_waitcnt vmcnt(0)" ::: "memory"); }
        __builtin_amdgcn_sched_barrier(0);
        __builtin_amdgcn_s_barrier();

        sl_t += 16384; if (sl_t == 49152) sl_t = 0;
        sl_p += 16384; if (sl_p == 49152) sl_p = 0;
    }
#undef STG1

    // epilogue: n even = gate frag, n+1 = up frag (same 16 cols)
#pragma unroll
    for (int m = 0; m < 4; m++) {
#pragma unroll
        for (int np = 0; np < 2; np++) {
            f32x4 g4 = acc[m][np * 2];
            f32x4 u4 = acc[m][np * 2 + 1];
            int icol = cb * 64 + (wc * 2 + np) * 16 + l16;
#pragma unroll
            for (int j2 = 0; j2 < 4; j2++) {
                int grow = rb * 128 + wr * 64 + m * 16 + lg * 4 + j2;
                if (grow < cnt_e) {
                    float gt = g4[j2], up = u4[j2];
                    float s = gt / (1.f + __expf(-gt));
                    act[(size_t)(off_e + grow) * IDIM + icol] = f2bf(s * up);
                }
            }
        }
    }
}

// ---------------- GEMM2 + weighted scatter ----------------
__global__ void __launch_bounds__(256, 3) gemm2_scatter(
    const unsigned short* __restrict__ act,
    const unsigned short* __restrict__ w2b,
    const int* __restrict__ tok,
    const float* __restrict__ wgt,
    const int* __restrict__ cnt,
    const int* __restrict__ off,
    float* __restrict__ out) {
    const int bid = blockIdx.x;
    const int e = bid & 7;       // XCD pin
    const int j = bid >> 3;
    const int rb = j >> 4;       // rb-major
    const int cb = j & 15;       // 0..15 (16*128 = 2048 out cols)
    const int cnt_e = cnt[e];
    if (rb * 128 >= cnt_e) return;
    const int off_e = off[e];
    const int NT = IDIM / 32;    // 44

    __shared__ __align__(16) char smem[49152];
    __shared__ int toks[128];
    __shared__ float wgts[128];

    const int tid = threadIdx.x;
    const int w = tid >> 6, lane = tid & 63;
    if (tid < 128) {
        int slot = rb * 128 + tid;
        bool v = slot < cnt_e;
        toks[tid] = v ? tok[e * CAP + slot] : 0;
        wgts[tid] = v ? wgt[e * CAP + slot] : 0.f;
    }
    __syncthreads();

    const int o0 = w * 1024 + lane * 16;
    const int row0 = o0 >> 6, g0 = ((o0 >> 4) & 3) ^ ((row0 >> 1) & 3);
    const int o1 = 4096 + o0;
    const int row1 = o1 >> 6, g1 = ((o1 >> 4) & 3) ^ ((row1 >> 1) & 3);

    const int s0 = rb * 128 + row0, s1 = rb * 128 + row1;
    const size_t pa0 = (size_t)(off_e + (s0 < cnt_e ? s0 : 0)) * IDIM + g0 * 8;
    const size_t pa1 = (size_t)(off_e + (s1 < cnt_e ? s1 : 0)) * IDIM + g1 * 8;
    const size_t w2base = (size_t)e * KDIM * IDIM;
    const size_t pb0 = w2base + (size_t)(cb * 128 + row0) * IDIM + g0 * 8;
    const size_t pb1 = w2base + (size_t)(cb * 128 + row1) * IDIM + g1 * 8;

    const int wr = w >> 1, wc = w & 1;
    const int l16 = lane & 15, lg = lane >> 4;
    int aoff[4], boff[4];
#pragma unroll
    for (int m = 0; m < 4; m++) {
        int r = wr * 64 + m * 16 + l16;
        aoff[m] = r * 64 + ((lg ^ ((r >> 1) & 3)) * 16);
    }
#pragma unroll
    for (int n = 0; n < 4; n++) {
        int r = wc * 64 + n * 16 + l16;
        boff[n] = 8192 + r * 64 + ((lg ^ ((r >> 1) & 3)) * 16);
    }

    f32x4 acc[4][4];
#pragma unroll
    for (int m = 0; m < 4; m++)
#pragma unroll
        for (int n = 0; n < 4; n++) acc[m][n] = {0.f, 0.f, 0.f, 0.f};

#define STG2(t, base) { const int kof_ = (t) * 32; char* b_ = smem + (base); \
    gload16(act + pa0 + kof_, b_ + w * 1024); \
    gload16(act + pa1 + kof_, b_ + 4096 + w * 1024); \
    gload16(w2b + pb0 + kof_, b_ + 8192 + w * 1024); \
    gload16(w2b + pb1 + kof_, b_ + 12288 + w * 1024); }

    STG2(0, 0); STG2(1, 16384);
    asm volatile("s_waitcnt vmcnt(4)" ::: "memory");
    __builtin_amdgcn_sched_barrier(0);
    __builtin_amdgcn_s_barrier();

    int sl_t = 0;
    int sl_p = 32768;

#pragma unroll 1
    for (int t = 0; t < NT; ++t) {
        if (t + 2 < NT) STG2(t + 2, sl_p);
        __builtin_amdgcn_sched_barrier(0);

        const char* db = smem + sl_t;
        bf16x8 af[4], bf[4];
#pragma unroll
        for (int m = 0; m < 4; m++) af[m] = *(const bf16x8*)(db + aoff[m]);
#pragma unroll
        for (int n = 0; n < 4; n++) bf[n] = *(const bf16x8*)(db + boff[n]);
        __builtin_amdgcn_s_setprio(1);
#pragma unroll
        for (int m = 0; m < 4; m++)
#pragma unroll
            for (int n = 0; n < 4; n++)
                acc[m][n] = __builtin_amdgcn_mfma_f32_16x16x32_bf16(af[m], bf[n], acc[m][n], 0, 0, 0);
        __builtin_amdgcn_s_setprio(0);
        __builtin_amdgcn_sched_barrier(0);
        if (t + 2 < NT)      { asm volatile("s_waitcnt vmcnt(4)" ::: "memory"); }
        else if (t + 1 < NT) { asm volatile("s_waitcnt vmcnt(0)" ::: "memory"); }
        __builtin_amdgcn_sched_barrier(0);
        __builtin_amdgcn_s_barrier();

        sl_t += 16384; if (sl_t == 49152) sl_t = 0;
        sl_p += 16384; if (sl_p == 49152) sl_p = 0;
    }
#undef STG2

    // scatter: out[token, k] += weight * y  (TOPK=2, fp32 atomic add, commutative)
#pragma unroll
    for (int m = 0; m < 4; m++) {
#pragma unroll
        for (int n = 0; n < 4; n++) {
            int kcol = cb * 128 + wc * 64 + n * 16 + l16;
#pragma unroll
            for (int j2 = 0; j2 < 4; j2++) {
                int lrow = wr * 64 + m * 16 + lg * 4 + j2;
                if (rb * 128 + lrow < cnt_e) {
                    atomicAdd(&out[(size_t)toks[lrow] * KDIM + kcol],
                              wgts[lrow] * acc[m][n][j2]);
                }
            }
        }
    }
}

extern "C" void kernel_launch(void* const* d_in, const int* in_sizes, int n_in,
                              void* d_out, int out_size, void* d_ws, size_t ws_size,
                              hipStream_t stream) {
    const float* hs  = (const float*)d_in[0];
    const float* w1  = (const float*)d_in[1];
    const float* w2  = (const float*)d_in[2];
    const float* tw  = (const float*)d_in[3];
    const int*   ids = (const int*)d_in[4];
    float* out = (float*)d_out;

    char* ws = (char*)d_ws;
    unsigned short* w1b  = (unsigned short*)(ws);                  //  92,274,688
    unsigned short* w2b  = (unsigned short*)(ws + 92274688ull);    //  46,137,344
    unsigned short* hsb  = (unsigned short*)(ws + 138412032ull);   //  16,777,216
    unsigned short* actb = (unsigned short*)(ws + 155189248ull);   //  23,068,672
    int*   tokb = (int*)  (ws + 178257920ull);
    float* wgtb = (float*)(ws + 178520064ull);
    int*   cntb = (int*)  (ws + 178782208ull);
    int*   offb = (int*)  (ws + 178782240ull);

    hipMemsetAsync(d_out, 0, (size_t)MTOK * KDIM * sizeof(float), stream);
    hipMemsetAsync(cntb, 0, 64, stream);

    conv_bf16<<<4096, 256, 0, stream>>>(w1, w1b, EXPERTS * NDIM * KDIM / 4);
    conv_bf16<<<2048, 256, 0, stream>>>(w2, w2b, EXPERTS * KDIM * IDIM / 4);
    conv_bf16<<<1024, 256, 0, stream>>>(hs, hsb, MTOK * KDIM / 4);

    router<<<MTOK / 256, 256, 0, stream>>>(tw, ids, tokb, wgtb, cntb);
    scan_off<<<1, 64, 0, stream>>>(cntb, offb);

    // linear grids with bid%8 == expert  (expert->XCD pinning)
    gemm1_silu<<<dim3(22 * 64 * 8, 1, 1), 256, 0, stream>>>(hsb, w1b, tokb, cntb, offb, actb);
    gemm2_scatter<<<dim3(16 * 64 * 8, 1, 1), 256, 0, stream>>>(actb, w2b, tokb, wgtb, cntb, offb, out);
}